// Round 8
// baseline (28820.197 us; speedup 1.0000x reference)
//
#include <hip/hip_runtime.h>
#include <stdint.h>

typedef unsigned short ushort_t;
typedef _Float16 f16_t;
typedef __attribute__((ext_vector_type(2))) _Float16 half2;
typedef __attribute__((ext_vector_type(8))) _Float16 half8;
typedef __attribute__((ext_vector_type(4))) float f32x4;

#define T_SEQ 4096
#define IN_SZ 512
#define H1 1024
#define H2 2048
#define G1 (4*H1)   // 4096
#define G2 (4*H2)   // 8192
#define OUT_SZ 512
#define L1OUT 1024

#define SENT 0xAAAAAAAAu

__device__ __forceinline__ float f16_val(ushort_t v) {
    union { ushort_t u; _Float16 h; } x; x.u = v; return (float)x.h;
}
__device__ __forceinline__ half2 u2h(uint32_t w) {
    union { uint32_t u; half2 h; } x; x.u = w; return x.h;
}
__device__ __forceinline__ uint32_t pack_f16(float a, float b) {
    auto h = __builtin_amdgcn_cvt_pkrtz(a, b);   // __fp16 ext_vector(2) on gfx950
    union { decltype(h) h; uint32_t u; } x; x.h = h; return x.u;
}
// fast gate math
__device__ __forceinline__ float fsig(float x) {
    return __builtin_amdgcn_rcpf(1.0f + __expf(-x));
}
__device__ __forceinline__ float ftanh(float x) {
    return 1.0f - 2.0f * __builtin_amdgcn_rcpf(__expf(2.0f * x) + 1.0f);
}

// 2 MACs: acc += w·h for one packed f16 pair
__device__ __forceinline__ void dot2(float& acc, uint32_t w, uint32_t h) {
#if defined(__has_builtin) && __has_builtin(__builtin_amdgcn_fdot2)
    acc = __builtin_amdgcn_fdot2(u2h(w), u2h(h), acc, false);
#else
    half2 a = u2h(w), b = u2h(h);
    acc = fmaf((float)a.x, (float)b.x, acc);
    acc = fmaf((float)a.y, (float)b.y, acc);
#endif
}
#define DOT4(ACC, W, Hv) do { dot2(ACC, (W).x, (Hv).x); dot2(ACC, (W).y, (Hv).y); \
                              dot2(ACC, (W).z, (Hv).z); dot2(ACC, (W).w, (Hv).w); } while (0)

// ---------------- f32 -> f16 conversion ----------------
__global__ __launch_bounds__(256) void cvt_f16_kernel(const float* __restrict__ in,
                                                      f16_t* __restrict__ out, int n) {
    int i = blockIdx.x * 256 + threadIdx.x;
    int stride = gridDim.x * 256;
    for (; i < n; i += stride) out[i] = (f16_t)in[i];
}

// ---------------- f16 MFMA GEMM: C[M,N] = A[M,K] * B[N,K]^T + bias_a + bias_b, f16 out ----------
__global__ __launch_bounds__(256) void gemm_bt_kernel(const f16_t* __restrict__ A,
                                                      const f16_t* __restrict__ B,
                                                      f16_t* __restrict__ Cb,
                                                      const float* __restrict__ bias_a,
                                                      const float* __restrict__ bias_b,
                                                      int M, int N, int K) {
    int tid  = threadIdx.x;
    int wave = tid >> 6;
    int lane = tid & 63;
    int l15  = lane & 15;
    int quad = lane >> 4;
    int m0 = blockIdx.y * 64 + wave * 16;
    int n0 = blockIdx.x * 64;

    const f16_t* pa = A + (size_t)(m0 + l15) * K + quad * 8;
    f32x4 acc[4];
    #pragma unroll
    for (int i = 0; i < 4; ++i) acc[i] = (f32x4){0.f, 0.f, 0.f, 0.f};

    for (int kc = 0; kc < K; kc += 32) {
        half8 a = *(const half8*)(pa + kc);
        #pragma unroll
        for (int nf = 0; nf < 4; ++nf) {
            const f16_t* pb = B + (size_t)(n0 + nf * 16 + l15) * K + quad * 8 + kc;
            half8 b = *(const half8*)pb;
            acc[nf] = __builtin_amdgcn_mfma_f32_16x16x32_f16(a, b, acc[nf], 0, 0, 0);
        }
    }

    int rbase = quad * 4;
    #pragma unroll
    for (int nf = 0; nf < 4; ++nf) {
        int n = n0 + nf * 16 + l15;
        float bb = bias_a[n] + bias_b[n];
        #pragma unroll
        for (int r = 0; r < 4; ++r) {
            int m = m0 + rbase + r;
            Cb[(size_t)m * N + n] = (f16_t)(acc[nf][r] + bb);
        }
    }
}

// ---------------- Fused 2-layer LSTM recurrence: ONE poll round + ONE barrier per iteration ----
// 256 blocks x 256 threads (1 block/CU, persistent). Block b owns h1 units [4b,4b+4),
// h2 units [8b,8b+8). Iteration s (s = 0..T+1):
//   poll h1[s-1] AND h2[s-3] together (both published >= ~1 full period ago -> first-try hit)
//   stage both into parity LDS bufs, ONE barrier
//   h1[s] = gates(whh1·h1[s-1] + pre1[s]) -> publish IMMEDIATELY (minimizes h1-chain offset)
//   pre2[s-1] = wih2-slice·h1[s-1]        -> kept in registers for next iteration
//   h2[s-2] = gates(whh2·h2[s-3] + pre2_prev) -> publish
// whh2 gates 1..3 stream from per-XCD L2 into regs, issued right after poll success (drain
// hidden behind h1/pre2 compute). Tight-spin polls (no s_sleep). comm f32, 0xAA sentinel.
__global__ __launch_bounds__(256, 1) void fused_lstm_kernel(
        const f16_t* __restrict__ pre1,       // f16 [T, 4096]
        const ushort_t* __restrict__ whh1h,   // f16 bits [4096, 1024]
        const ushort_t* __restrict__ wih2h,   // f16 bits [8192, 1024]
        const ushort_t* __restrict__ whh2h,   // f16 bits [8192, 2048]
        const float* __restrict__ bih2,
        const float* __restrict__ bhh2,
        uint32_t* __restrict__ comm1,         // f32 bits [T, 1024], pre-poisoned 0xAA
        uint32_t* __restrict__ comm2,         // f32 bits [T, 2048], pre-poisoned 0xAA
        int T) {
    extern __shared__ char smem[];
    uint32_t* whh1_w = (uint32_t*)smem;             // [16][512]  f16-pair words (32KB)
    uint32_t* wih2_w = whh1_w + 16 * 512;           // [32][512]  (64KB)
    uint32_t* whh2_w = wih2_w + 32 * 512;           // [8][1024]  gate0 (32KB)
    uint32_t* h1b    = whh2_w + 8 * 1024;           // [2][512]   packed h1 (4KB)
    uint32_t* h2b    = h1b + 2 * 512;               // [2][1024]  packed h2 (8KB)

    int tid = threadIdx.x;
    int blk = blockIdx.x;
    int u1  = tid >> 6;          // h1 unit (0..3), 64 lanes
    int ln1 = tid & 63;
    int u2l = tid >> 5;          // h2 unit (0..7), 32 lanes
    int ln2 = tid & 31;
    int wv  = tid >> 6;          // wave id

    // ---- stage resident weights into LDS ----
    #pragma unroll
    for (int i = 0; i < 8; ++i) {            // whh1: 16 rows x 128 uint4
        int idx = tid + i * 256, r = idx >> 7, ch = idx & 127;
        size_t R = (size_t)(r & 3) * H1 + blk * 4 + (r >> 2);
        *(uint4*)&whh1_w[r * 512 + ch * 4] = *(const uint4*)(whh1h + R * H1 + ch * 8);
    }
    #pragma unroll
    for (int i = 0; i < 16; ++i) {           // wih2: 32 rows x 128 uint4
        int idx = tid + i * 256, r = idx >> 7, ch = idx & 127;
        size_t R = (size_t)(r & 3) * H2 + blk * 8 + (r >> 2);
        *(uint4*)&wih2_w[r * 512 + ch * 4] = *(const uint4*)(wih2h + R * H1 + ch * 8);
    }
    #pragma unroll
    for (int i = 0; i < 8; ++i) {            // whh2 gate0: 8 rows x 256 uint4
        int idx = tid + i * 256, r = idx >> 8, ch = idx & 255;
        size_t R = (size_t)(blk * 8 + r);
        *(uint4*)&whh2_w[r * 1024 + ch * 4] = *(const uint4*)(whh2h + R * H2 + ch * 8);
    }

    float b2g[4];
    {
        int U = blk * 8 + u2l;
        #pragma unroll
        for (int g = 0; g < 4; ++g) b2g[g] = bih2[g * H2 + U] + bhh2[g * H2 + U];
    }

    float pc[4] = {0.f, 0.f, 0.f, 0.f};
    if (ln1 == 0) {
        #pragma unroll
        for (int g = 0; g < 4; ++g)
            pc[g] = f16_val(((const ushort_t*)pre1)[(size_t)0 * G1 + g * H1 + blk * 4 + u1]);
    }

    float c1 = 0.0f;     // ln1==0
    float c2 = 0.0f;     // ln2==0
    float pbp[8];        // pre2[s-2] carried from previous iteration (wave-uniform)
    #pragma unroll
    for (int d = 0; d < 8; ++d) pbp[d] = 0.f;

    for (int s = 0; s <= T + 1; ++s) {
        bool need1 = (s >= 1) & (s <= T);       // h1[s-1] consumer (h1 dot s<T, pre2 s<=T)
        bool need2 = (s >= 3) & (s <= T + 1);   // h2[s-3] consumer
        int i1 = need1 ? (s - 1) : 0;
        int i2 = need2 ? (s - 3) : 0;

        // ---- unified tight-spin poll: h1[s-1] + h2[s-3] (12 loads in flight / round) ----
        const uint64_t* s1 = (const uint64_t*)(comm1 + (size_t)i1 * H1);
        const uint64_t* s2 = (const uint64_t*)(comm2 + (size_t)i2 * H2);
        uint64_t q1[2], q2[4];
        for (;;) {
            q1[0] = __hip_atomic_load(&s1[tid],       __ATOMIC_RELAXED, __HIP_MEMORY_SCOPE_AGENT);
            q1[1] = __hip_atomic_load(&s1[tid + 256], __ATOMIC_RELAXED, __HIP_MEMORY_SCOPE_AGENT);
            #pragma unroll
            for (int k = 0; k < 4; ++k)
                q2[k] = __hip_atomic_load(&s2[tid + k * 256], __ATOMIC_RELAXED,
                                          __HIP_MEMORY_SCOPE_AGENT);
            bool bad = false;
            if (need1) {
                bad |= ((uint32_t)q1[0] == SENT) | ((uint32_t)(q1[0] >> 32) == SENT)
                     | ((uint32_t)q1[1] == SENT) | ((uint32_t)(q1[1] >> 32) == SENT);
            }
            if (need2) {
                #pragma unroll
                for (int k = 0; k < 4; ++k)
                    bad |= ((uint32_t)q2[k] == SENT) | ((uint32_t)(q2[k] >> 32) == SENT);
            }
            if (!bad) break;
        }

        // ---- issue streamed whh2 gates 1..3 (L2) + pre1[s+1] prefetch; drain behind h1/pre2 ----
        uint4 wreg[24];
        if (need2) {
            #pragma unroll
            for (int g = 1; g < 4; ++g) {
                size_t R = (size_t)g * H2 + blk * 8 + u2l;
                #pragma unroll
                for (int j = 0; j < 8; ++j)
                    wreg[(g - 1) * 8 + j] =
                        *(const uint4*)(whh2h + R * H2 + ln2 * 8 + j * 256);
            }
        }
        float pn[4] = {0.f, 0.f, 0.f, 0.f};
        if (ln1 == 0) {
            int row = (s + 1 < T) ? s + 1 : T - 1;
            #pragma unroll
            for (int g = 0; g < 4; ++g)
                pn[g] = f16_val(((const ushort_t*)pre1)[(size_t)row * G1 + g * H1 + blk * 4 + u1]);
        }

        // ---- stage polled h into parity LDS bufs (packed f16) ----
        if (need1) {
            uint32_t* d = h1b + (s & 1) * 512;
            union { uint64_t q; float f[2]; } x;
            x.q = q1[0]; d[tid]       = pack_f16(x.f[0], x.f[1]);
            x.q = q1[1]; d[tid + 256] = pack_f16(x.f[0], x.f[1]);
        }
        if (need2) {
            uint32_t* d = h2b + (s & 1) * 1024;
            #pragma unroll
            for (int k = 0; k < 4; ++k) {
                union { uint64_t q; float f[2]; } x; x.q = q2[k];
                d[tid + k * 256] = pack_f16(x.f[0], x.f[1]);
            }
        }
        __syncthreads();   // the ONLY barrier per iteration

        const uint32_t* h1p = h1b + (s & 1) * 512;
        uint4 hA, hB;
        if (need1) {
            hA = *(const uint4*)&h1p[ln1 * 4];
            hB = *(const uint4*)&h1p[ln1 * 4 + 256];
        }

        // ---- h1[s]: dot + gates + IMMEDIATE publish (binding chain; minimal offset) ----
        if (s < T) {
            float a0 = 0.f, a1 = 0.f, a2 = 0.f, a3 = 0.f;
            if (s >= 1) {
                uint4 w;
                w = *(const uint4*)&whh1_w[(u1 * 4 + 0) * 512 + ln1 * 4];       DOT4(a0, w, hA);
                w = *(const uint4*)&whh1_w[(u1 * 4 + 0) * 512 + ln1 * 4 + 256]; DOT4(a0, w, hB);
                w = *(const uint4*)&whh1_w[(u1 * 4 + 1) * 512 + ln1 * 4];       DOT4(a1, w, hA);
                w = *(const uint4*)&whh1_w[(u1 * 4 + 1) * 512 + ln1 * 4 + 256]; DOT4(a1, w, hB);
                w = *(const uint4*)&whh1_w[(u1 * 4 + 2) * 512 + ln1 * 4];       DOT4(a2, w, hA);
                w = *(const uint4*)&whh1_w[(u1 * 4 + 2) * 512 + ln1 * 4 + 256]; DOT4(a2, w, hB);
                w = *(const uint4*)&whh1_w[(u1 * 4 + 3) * 512 + ln1 * 4];       DOT4(a3, w, hA);
                w = *(const uint4*)&whh1_w[(u1 * 4 + 3) * 512 + ln1 * 4 + 256]; DOT4(a3, w, hB);
            }
            #pragma unroll
            for (int off = 32; off > 0; off >>= 1) {
                a0 += __shfl_down(a0, off, 64); a1 += __shfl_down(a1, off, 64);
                a2 += __shfl_down(a2, off, 64); a3 += __shfl_down(a3, off, 64);
            }
            if (ln1 == 0) {
                float iv = fsig(pc[0] + a0);
                float fv = fsig(pc[1] + a1);
                float gv = ftanh(pc[2] + a2);
                float ov = fsig(pc[3] + a3);
                c1 = fv * c1 + iv * gv;
                float h = ov * ftanh(c1);
                union { float f; uint32_t u; } x; x.f = h;
                __hip_atomic_store(&comm1[(size_t)s * H1 + blk * 4 + u1], x.u,
                                   __ATOMIC_RELAXED, __HIP_MEMORY_SCOPE_AGENT);
            }
        }

        // ---- pre2[s-1] = this block's 32 wih2 rows · h1[s-1]; kept for NEXT iteration ----
        float pbc[8];
        if (need1) {
            float pv[8];
            #pragma unroll
            for (int d = 0; d < 8; ++d) pv[d] = 0.f;
            #pragma unroll
            for (int d = 0; d < 8; ++d) {
                int r = wv * 8 + d;
                uint4 w0 = *(const uint4*)&wih2_w[r * 512 + ln1 * 4];
                uint4 w1 = *(const uint4*)&wih2_w[r * 512 + ln1 * 4 + 256];
                DOT4(pv[d], w0, hA);
                DOT4(pv[d], w1, hB);
            }
            #pragma unroll
            for (int off = 32; off > 0; off >>= 1) {
                #pragma unroll
                for (int d = 0; d < 8; ++d) pv[d] += __shfl_down(pv[d], off, 64);
            }
            #pragma unroll
            for (int d = 0; d < 8; ++d) pbc[d] = __shfl(pv[d], 0, 64);
        }

        // ---- h2[s-2] = gates(whh2·h2[s-3] + pre2[s-2]) ----
        if (s >= 2) {
            float b0 = 0.f, b1 = 0.f, b2 = 0.f, b3 = 0.f;
            if (need2) {
                const uint32_t* h2p = h2b + (s & 1) * 1024;
                #pragma unroll
                for (int j = 0; j < 8; ++j) {
                    uint4 hx = *(const uint4*)&h2p[ln2 * 4 + j * 128];
                    uint4 w0 = *(const uint4*)&whh2_w[u2l * 1024 + ln2 * 4 + j * 128];
                    DOT4(b0, w0, hx);
                    DOT4(b1, wreg[j], hx);
                    DOT4(b2, wreg[8 + j], hx);
                    DOT4(b3, wreg[16 + j], hx);
                }
            }
            #pragma unroll
            for (int off = 16; off > 0; off >>= 1) {
                b0 += __shfl_down(b0, off, 32); b1 += __shfl_down(b1, off, 32);
                b2 += __shfl_down(b2, off, 32); b3 += __shfl_down(b3, off, 32);
            }
            if (ln2 == 0) {
                int half = u2l & 1;
                float iv = fsig(pbp[half * 4 + 0] + b2g[0] + b0);
                float fv = fsig(pbp[half * 4 + 1] + b2g[1] + b1);
                float gv = ftanh(pbp[half * 4 + 2] + b2g[2] + b2);
                float ov = fsig(pbp[half * 4 + 3] + b2g[3] + b3);
                c2 = fv * c2 + iv * gv;
                float h = ov * ftanh(c2);
                union { float f; uint32_t u; } x; x.f = h;
                __hip_atomic_store(&comm2[(size_t)(s - 2) * H2 + blk * 8 + u2l], x.u,
                                   __ATOMIC_RELAXED, __HIP_MEMORY_SCOPE_AGENT);
            }
        }

        // carry pre2 and pre1 pipelines
        if (need1) {
            #pragma unroll
            for (int d = 0; d < 8; ++d) pbp[d] = pbc[d];
        }
        #pragma unroll
        for (int g = 0; g < 4; ++g) pc[g] = pn[g];
    }
}

// ---------------- small matvec ----------------
__global__ __launch_bounds__(256) void linear_vec_kernel(const float* __restrict__ W,
                                                         const float* __restrict__ bias,
                                                         const float* __restrict__ x,
                                                         float* __restrict__ out,
                                                         int N, int K) {
    int wave = threadIdx.x >> 6;
    int lane = threadIdx.x & 63;
    int j = blockIdx.x * 4 + wave;
    if (j >= N) return;
    const float* wr = W + (size_t)j * K;
    float s = 0.0f;
    for (int k = lane; k < K; k += 64) s += wr[k] * x[k];
    #pragma unroll
    for (int off = 32; off > 0; off >>= 1) s += __shfl_down(s, off, 64);
    if (lane == 0) out[j] = s + bias[j];
}

extern "C" void kernel_launch(void* const* d_in, const int* in_sizes, int n_in,
                              void* d_out, int out_size, void* d_ws, size_t ws_size,
                              hipStream_t stream) {
    const float* x_f    = (const float*)d_in[0];
    const float* wih1_f = (const float*)d_in[1];
    const float* whh1_f = (const float*)d_in[2];
    const float* bih1   = (const float*)d_in[3];
    const float* bhh1   = (const float*)d_in[4];
    const float* wih2_f = (const float*)d_in[5];
    const float* whh2_f = (const float*)d_in[6];
    const float* bih2   = (const float*)d_in[7];
    const float* bhh2   = (const float*)d_in[8];
    const float* wl1    = (const float*)d_in[9];
    const float* bl1    = (const float*)d_in[10];
    const float* wl2    = (const float*)d_in[11];
    const float* bl2    = (const float*)d_in[12];

    uint8_t* base = (uint8_t*)d_ws;
    size_t off = 0;
    auto alloc = [&](size_t bytes) { size_t o = off; off = (off + bytes + 255) & ~(size_t)255; return o; };

    size_t pre1_off  = alloc((size_t)T_SEQ * G1 * 2);   // f16 [T,4096]
    size_t comm1_off = alloc((size_t)T_SEQ * H1 * 4);   // f32 [T,1024]
    size_t comm2_off = alloc((size_t)T_SEQ * H2 * 4);   // f32 [T,2048]
    size_t whh1_off  = alloc((size_t)G1 * H1 * 2);
    size_t whh2_off  = alloc((size_t)G2 * H2 * 2);
    size_t wih1_off  = alloc((size_t)G1 * IN_SZ * 2);
    size_t wih2_off  = alloc((size_t)G2 * H1 * 2);
    size_t xb_off    = alloc((size_t)T_SEQ * IN_SZ * 2);
    size_t p1_off    = alloc((size_t)L1OUT * 4);

    f16_t*    pre1  = (f16_t*)(base + pre1_off);
    uint32_t* comm1 = (uint32_t*)(base + comm1_off);
    uint32_t* comm2 = (uint32_t*)(base + comm2_off);
    ushort_t* whh1h = (ushort_t*)(base + whh1_off);
    ushort_t* whh2h = (ushort_t*)(base + whh2_off);
    f16_t*    wih1h = (f16_t*)(base + wih1_off);
    ushort_t* wih2h = (ushort_t*)(base + wih2_off);
    f16_t*    xb    = (f16_t*)(base + xb_off);
    float*    p1    = (float*)(base + p1_off);

    // poison sentinel comm buffers (data-as-signal)
    (void)hipMemsetAsync(comm1, 0xAA, (size_t)T_SEQ * H1 * 4, stream);
    (void)hipMemsetAsync(comm2, 0xAA, (size_t)T_SEQ * H2 * 4, stream);

    // f32 -> f16 conversions
    cvt_f16_kernel<<<2048, 256, 0, stream>>>(x_f,    xb,            T_SEQ * IN_SZ);
    cvt_f16_kernel<<<2048, 256, 0, stream>>>(wih1_f, wih1h,         G1 * IN_SZ);
    cvt_f16_kernel<<<2048, 256, 0, stream>>>(whh1_f, (f16_t*)whh1h, G1 * H1);
    cvt_f16_kernel<<<2048, 256, 0, stream>>>(wih2_f, (f16_t*)wih2h, G2 * H1);
    cvt_f16_kernel<<<4096, 256, 0, stream>>>(whh2_f, (f16_t*)whh2h, G2 * H2);

    // pre1 = x @ wih1^T + (bih1 + bhh1)   [f16 out]
    {
        dim3 grid(G1 / 64, T_SEQ / 64);
        gemm_bt_kernel<<<grid, 256, 0, stream>>>(xb, wih1h, pre1, bih1, bhh1,
                                                 T_SEQ, G1, IN_SZ);
    }

    // fused 2-layer recurrence: 256 blocks, 140KB dynamic LDS
    {
        size_t shmem = (size_t)(16 * 512 + 32 * 512 + 8 * 1024 + 2 * 512 + 2 * 1024) * 4;
        fused_lstm_kernel<<<256, 256, shmem, stream>>>(
            pre1, whh1h, wih2h, whh2h, bih2, bhh2, comm1, comm2, T_SEQ);
    }

    // p1 = wl1 . h2[T-1] + bl1 ; out = wl2 . p1 + bl2
    const float* h2_last = (const float*)(comm2 + (size_t)(T_SEQ - 1) * H2);
    linear_vec_kernel<<<L1OUT / 4, 256, 0, stream>>>(wl1, bl1, h2_last, p1, L1OUT, H2);
    linear_vec_kernel<<<OUT_SZ / 4, 256, 0, stream>>>(wl2, bl2, p1, (float*)d_out, OUT_SZ, L1OUT);

    (void)in_sizes; (void)n_in; (void)out_size; (void)ws_size;
}

// Round 9
// 17714.163 us; speedup vs baseline: 1.6270x; 1.6270x over previous
//
#include <hip/hip_runtime.h>
#include <stdint.h>

typedef unsigned short ushort_t;
typedef _Float16 f16_t;
typedef __attribute__((ext_vector_type(2))) _Float16 half2;
typedef __attribute__((ext_vector_type(8))) _Float16 half8;
typedef __attribute__((ext_vector_type(4))) float f32x4;

#define T_SEQ 4096
#define IN_SZ 512
#define H1 1024
#define H2 2048
#define G1 (4*H1)   // 4096
#define G2 (4*H2)   // 8192
#define OUT_SZ 512
#define L1OUT 1024

#define SENT 0xAAAAAAAAu

__device__ __forceinline__ float f16_val(ushort_t v) {
    union { ushort_t u; _Float16 h; } x; x.u = v; return (float)x.h;
}
__device__ __forceinline__ half2 u2h(uint32_t w) {
    union { uint32_t u; half2 h; } x; x.u = w; return x.h;
}
__device__ __forceinline__ uint32_t pack_f16(float a, float b) {
    auto h = __builtin_amdgcn_cvt_pkrtz(a, b);   // __fp16 ext_vector(2) on gfx950
    union { decltype(h) h; uint32_t u; } x; x.h = h; return x.u;
}
// fast gate math
__device__ __forceinline__ float fsig(float x) {
    return __builtin_amdgcn_rcpf(1.0f + __expf(-x));
}
__device__ __forceinline__ float ftanh(float x) {
    return 1.0f - 2.0f * __builtin_amdgcn_rcpf(__expf(2.0f * x) + 1.0f);
}

// 2 MACs: acc += w·h for one packed f16 pair
__device__ __forceinline__ void dot2(float& acc, uint32_t w, uint32_t h) {
#if defined(__has_builtin) && __has_builtin(__builtin_amdgcn_fdot2)
    acc = __builtin_amdgcn_fdot2(u2h(w), u2h(h), acc, false);
#else
    half2 a = u2h(w), b = u2h(h);
    acc = fmaf((float)a.x, (float)b.x, acc);
    acc = fmaf((float)a.y, (float)b.y, acc);
#endif
}
#define DOT4(ACC, W, Hv) do { dot2(ACC, (W).x, (Hv).x); dot2(ACC, (W).y, (Hv).y); \
                              dot2(ACC, (W).z, (Hv).z); dot2(ACC, (W).w, (Hv).w); } while (0)

// ---------------- f32 -> f16 conversion ----------------
__global__ __launch_bounds__(256) void cvt_f16_kernel(const float* __restrict__ in,
                                                      f16_t* __restrict__ out, int n) {
    int i = blockIdx.x * 256 + threadIdx.x;
    int stride = gridDim.x * 256;
    for (; i < n; i += stride) out[i] = (f16_t)in[i];
}

// ---------------- f16 MFMA GEMM: C[M,N] = A[M,K] * B[N,K]^T + bias_a + bias_b, f16 out ----------
__global__ __launch_bounds__(256) void gemm_bt_kernel(const f16_t* __restrict__ A,
                                                      const f16_t* __restrict__ B,
                                                      f16_t* __restrict__ Cb,
                                                      const float* __restrict__ bias_a,
                                                      const float* __restrict__ bias_b,
                                                      int M, int N, int K) {
    int tid  = threadIdx.x;
    int wave = tid >> 6;
    int lane = tid & 63;
    int l15  = lane & 15;
    int quad = lane >> 4;
    int m0 = blockIdx.y * 64 + wave * 16;
    int n0 = blockIdx.x * 64;

    const f16_t* pa = A + (size_t)(m0 + l15) * K + quad * 8;
    f32x4 acc[4];
    #pragma unroll
    for (int i = 0; i < 4; ++i) acc[i] = (f32x4){0.f, 0.f, 0.f, 0.f};

    for (int kc = 0; kc < K; kc += 32) {
        half8 a = *(const half8*)(pa + kc);
        #pragma unroll
        for (int nf = 0; nf < 4; ++nf) {
            const f16_t* pb = B + (size_t)(n0 + nf * 16 + l15) * K + quad * 8 + kc;
            half8 b = *(const half8*)pb;
            acc[nf] = __builtin_amdgcn_mfma_f32_16x16x32_f16(a, b, acc[nf], 0, 0, 0);
        }
    }

    int rbase = quad * 4;
    #pragma unroll
    for (int nf = 0; nf < 4; ++nf) {
        int n = n0 + nf * 16 + l15;
        float bb = bias_a[n] + bias_b[n];
        #pragma unroll
        for (int r = 0; r < 4; ++r) {
            int m = m0 + rbase + r;
            Cb[(size_t)m * N + n] = (f16_t)(acc[nf][r] + bb);
        }
    }
}

// ---------------- Fused 2-layer LSTM: ONE poll + ONE barrier per iteration, early publishes ----
// 256 blocks x 256 threads (1 block/CU, persistent). Block b owns h1 units [4b,4b+4),
// h2 units [8b,8b+8). Iteration s (s = 0..T+1):
//   prefetch wreg (whh2 gates 1..3, L2) + pre1[s+1]     [before poll: drain overlaps wait]
//   poll h1[s-1] AND h2[s-3] (s_sleep backoff), stage packed-f16, ONE barrier
//   h1[s]   = gates(whh1·h1[s-1] + pre1[s])     -> publish  (offset ~0.4us)
//   h2[s-2] = gates(whh2·h2[s-3] + pre2[s-2])   -> publish  (offset ~1.0us; pre2 in regs!)
//   pre2[s-1] = wih2-slice·h1[s-1]              -> registers for next iteration
// KEY (R8 post-mortem): publish-to-poll gap per chain must be ~a full period. h1: published
// early iter s, polled start iter s+1 -> gap ~P-0.4. h2[s-2]: published early iter s, polled
// start iter s+1 -> gap ~P-1.0. R8 published h2 at iteration END (gap ~0) and regressed 1.7x.
__global__ __launch_bounds__(256, 1) void fused_lstm_kernel(
        const f16_t* __restrict__ pre1,       // f16 [T, 4096]
        const ushort_t* __restrict__ whh1h,   // f16 bits [4096, 1024]
        const ushort_t* __restrict__ wih2h,   // f16 bits [8192, 1024]
        const ushort_t* __restrict__ whh2h,   // f16 bits [8192, 2048]
        const float* __restrict__ bih2,
        const float* __restrict__ bhh2,
        uint32_t* __restrict__ comm1,         // f32 bits [T, 1024], pre-poisoned 0xAA
        uint32_t* __restrict__ comm2,         // f32 bits [T, 2048], pre-poisoned 0xAA
        int T) {
    extern __shared__ char smem[];
    uint32_t* whh1_w = (uint32_t*)smem;             // [16][512]  f16-pair words (32KB)
    uint32_t* wih2_w = whh1_w + 16 * 512;           // [32][512]  (64KB)
    uint32_t* whh2_w = wih2_w + 32 * 512;           // [8][1024]  gate0 (32KB)
    uint32_t* h1b    = whh2_w + 8 * 1024;           // [2][512]   packed h1 (4KB)
    uint32_t* h2b    = h1b + 2 * 512;               // [2][1024]  packed h2 (8KB)

    int tid = threadIdx.x;
    int blk = blockIdx.x;
    int u1  = tid >> 6;          // h1 unit (0..3), 64 lanes
    int ln1 = tid & 63;
    int u2l = tid >> 5;          // h2 unit (0..7), 32 lanes
    int ln2 = tid & 31;
    int wv  = tid >> 6;          // wave id

    // ---- stage resident weights into LDS ----
    #pragma unroll
    for (int i = 0; i < 8; ++i) {            // whh1: 16 rows x 128 uint4
        int idx = tid + i * 256, r = idx >> 7, ch = idx & 127;
        size_t R = (size_t)(r & 3) * H1 + blk * 4 + (r >> 2);
        *(uint4*)&whh1_w[r * 512 + ch * 4] = *(const uint4*)(whh1h + R * H1 + ch * 8);
    }
    #pragma unroll
    for (int i = 0; i < 16; ++i) {           // wih2: 32 rows x 128 uint4
        int idx = tid + i * 256, r = idx >> 7, ch = idx & 127;
        size_t R = (size_t)(r & 3) * H2 + blk * 8 + (r >> 2);
        *(uint4*)&wih2_w[r * 512 + ch * 4] = *(const uint4*)(wih2h + R * H1 + ch * 8);
    }
    #pragma unroll
    for (int i = 0; i < 8; ++i) {            // whh2 gate0: 8 rows x 256 uint4
        int idx = tid + i * 256, r = idx >> 8, ch = idx & 255;
        size_t R = (size_t)(blk * 8 + r);
        *(uint4*)&whh2_w[r * 1024 + ch * 4] = *(const uint4*)(whh2h + R * H2 + ch * 8);
    }

    float b2g[4];
    {
        int U = blk * 8 + u2l;
        #pragma unroll
        for (int g = 0; g < 4; ++g) b2g[g] = bih2[g * H2 + U] + bhh2[g * H2 + U];
    }

    float pc[4] = {0.f, 0.f, 0.f, 0.f};
    if (ln1 == 0) {
        #pragma unroll
        for (int g = 0; g < 4; ++g)
            pc[g] = f16_val(((const ushort_t*)pre1)[(size_t)0 * G1 + g * H1 + blk * 4 + u1]);
    }

    float c1 = 0.0f;     // ln1==0
    float c2 = 0.0f;     // ln2==0
    float pbp[8];        // pre2[s-2] carried from previous iteration (wave-uniform)
    #pragma unroll
    for (int d = 0; d < 8; ++d) pbp[d] = 0.f;

    for (int s = 0; s <= T + 1; ++s) {
        bool need1 = (s >= 1) & (s <= T);       // h1[s-1] consumer
        bool need2 = (s >= 3) & (s <= T + 1);   // h2[s-3] consumer
        int i1 = need1 ? (s - 1) : 0;
        int i2 = need2 ? (s - 3) : 0;

        // ---- prefetch BEFORE the poll: streamed whh2 gates 1..3 (L2) + pre1[s+1] ----
        uint4 wreg[24];
        if (need2) {
            #pragma unroll
            for (int g = 1; g < 4; ++g) {
                size_t R = (size_t)g * H2 + blk * 8 + u2l;
                #pragma unroll
                for (int j = 0; j < 8; ++j)
                    wreg[(g - 1) * 8 + j] =
                        *(const uint4*)(whh2h + R * H2 + ln2 * 8 + j * 256);
            }
        }
        float pn[4] = {0.f, 0.f, 0.f, 0.f};
        if (ln1 == 0) {
            int row = (s + 1 < T) ? s + 1 : T - 1;
            #pragma unroll
            for (int g = 0; g < 4; ++g)
                pn[g] = f16_val(((const ushort_t*)pre1)[(size_t)row * G1 + g * H1 + blk * 4 + u1]);
        }

        // ---- unified poll (s_sleep backoff): h1[s-1] + h2[s-3] ----
        const uint64_t* s1 = (const uint64_t*)(comm1 + (size_t)i1 * H1);
        const uint64_t* s2 = (const uint64_t*)(comm2 + (size_t)i2 * H2);
        uint64_t q1[2], q2[4];
        for (;;) {
            q1[0] = __hip_atomic_load(&s1[tid],       __ATOMIC_RELAXED, __HIP_MEMORY_SCOPE_AGENT);
            q1[1] = __hip_atomic_load(&s1[tid + 256], __ATOMIC_RELAXED, __HIP_MEMORY_SCOPE_AGENT);
            #pragma unroll
            for (int k = 0; k < 4; ++k)
                q2[k] = __hip_atomic_load(&s2[tid + k * 256], __ATOMIC_RELAXED,
                                          __HIP_MEMORY_SCOPE_AGENT);
            bool bad = false;
            if (need1) {
                bad |= ((uint32_t)q1[0] == SENT) | ((uint32_t)(q1[0] >> 32) == SENT)
                     | ((uint32_t)q1[1] == SENT) | ((uint32_t)(q1[1] >> 32) == SENT);
            }
            if (need2) {
                #pragma unroll
                for (int k = 0; k < 4; ++k)
                    bad |= ((uint32_t)q2[k] == SENT) | ((uint32_t)(q2[k] >> 32) == SENT);
            }
            if (!bad) break;
            __builtin_amdgcn_s_sleep(1);
        }

        // ---- stage polled h into parity LDS bufs (packed f16) ----
        if (need1) {
            uint32_t* d = h1b + (s & 1) * 512;
            union { uint64_t q; float f[2]; } x;
            x.q = q1[0]; d[tid]       = pack_f16(x.f[0], x.f[1]);
            x.q = q1[1]; d[tid + 256] = pack_f16(x.f[0], x.f[1]);
        }
        if (need2) {
            uint32_t* d = h2b + (s & 1) * 1024;
            #pragma unroll
            for (int k = 0; k < 4; ++k) {
                union { uint64_t q; float f[2]; } x; x.q = q2[k];
                d[tid + k * 256] = pack_f16(x.f[0], x.f[1]);
            }
        }
        __syncthreads();   // the ONLY barrier per iteration

        const uint32_t* h1p = h1b + (s & 1) * 512;
        uint4 hA, hB;
        if (need1) {
            hA = *(const uint4*)&h1p[ln1 * 4];
            hB = *(const uint4*)&h1p[ln1 * 4 + 256];
        }

        // ---- h1[s]: dot + gates + immediate publish (chain offset ~0.4us) ----
        if (s < T) {
            float a0 = 0.f, a1 = 0.f, a2 = 0.f, a3 = 0.f;
            if (s >= 1) {
                uint4 w;
                w = *(const uint4*)&whh1_w[(u1 * 4 + 0) * 512 + ln1 * 4];       DOT4(a0, w, hA);
                w = *(const uint4*)&whh1_w[(u1 * 4 + 0) * 512 + ln1 * 4 + 256]; DOT4(a0, w, hB);
                w = *(const uint4*)&whh1_w[(u1 * 4 + 1) * 512 + ln1 * 4];       DOT4(a1, w, hA);
                w = *(const uint4*)&whh1_w[(u1 * 4 + 1) * 512 + ln1 * 4 + 256]; DOT4(a1, w, hB);
                w = *(const uint4*)&whh1_w[(u1 * 4 + 2) * 512 + ln1 * 4];       DOT4(a2, w, hA);
                w = *(const uint4*)&whh1_w[(u1 * 4 + 2) * 512 + ln1 * 4 + 256]; DOT4(a2, w, hB);
                w = *(const uint4*)&whh1_w[(u1 * 4 + 3) * 512 + ln1 * 4];       DOT4(a3, w, hA);
                w = *(const uint4*)&whh1_w[(u1 * 4 + 3) * 512 + ln1 * 4 + 256]; DOT4(a3, w, hB);
            }
            #pragma unroll
            for (int off = 32; off > 0; off >>= 1) {
                a0 += __shfl_down(a0, off, 64); a1 += __shfl_down(a1, off, 64);
                a2 += __shfl_down(a2, off, 64); a3 += __shfl_down(a3, off, 64);
            }
            if (ln1 == 0) {
                float iv = fsig(pc[0] + a0);
                float fv = fsig(pc[1] + a1);
                float gv = ftanh(pc[2] + a2);
                float ov = fsig(pc[3] + a3);
                c1 = fv * c1 + iv * gv;
                float h = ov * ftanh(c1);
                union { float f; uint32_t u; } x; x.f = h;
                __hip_atomic_store(&comm1[(size_t)s * H1 + blk * 4 + u1], x.u,
                                   __ATOMIC_RELAXED, __HIP_MEMORY_SCOPE_AGENT);
            }
        }

        // ---- h2[s-2] = gates(whh2·h2[s-3] + pre2[s-2]): EARLY publish (chain offset ~1us) ----
        if (s >= 2) {
            float b0 = 0.f, b1 = 0.f, b2 = 0.f, b3 = 0.f;
            if (need2) {
                const uint32_t* h2p = h2b + (s & 1) * 1024;
                #pragma unroll
                for (int j = 0; j < 8; ++j) {
                    uint4 hx = *(const uint4*)&h2p[ln2 * 4 + j * 128];
                    uint4 w0 = *(const uint4*)&whh2_w[u2l * 1024 + ln2 * 4 + j * 128];
                    DOT4(b0, w0, hx);
                    DOT4(b1, wreg[j], hx);
                    DOT4(b2, wreg[8 + j], hx);
                    DOT4(b3, wreg[16 + j], hx);
                }
            }
            #pragma unroll
            for (int off = 16; off > 0; off >>= 1) {
                b0 += __shfl_down(b0, off, 32); b1 += __shfl_down(b1, off, 32);
                b2 += __shfl_down(b2, off, 32); b3 += __shfl_down(b3, off, 32);
            }
            if (ln2 == 0) {
                int half = u2l & 1;
                float iv = fsig(pbp[half * 4 + 0] + b2g[0] + b0);
                float fv = fsig(pbp[half * 4 + 1] + b2g[1] + b1);
                float gv = ftanh(pbp[half * 4 + 2] + b2g[2] + b2);
                float ov = fsig(pbp[half * 4 + 3] + b2g[3] + b3);
                c2 = fv * c2 + iv * gv;
                float h = ov * ftanh(c2);
                union { float f; uint32_t u; } x; x.f = h;
                __hip_atomic_store(&comm2[(size_t)(s - 2) * H2 + blk * 8 + u2l], x.u,
                                   __ATOMIC_RELAXED, __HIP_MEMORY_SCOPE_AGENT);
            }
        }

        // ---- pre2[s-1] = wih2-slice · h1[s-1] (for NEXT iteration; off the publish path) ----
        if (need1) {
            float pv[8];
            #pragma unroll
            for (int d = 0; d < 8; ++d) pv[d] = 0.f;
            #pragma unroll
            for (int d = 0; d < 8; ++d) {
                int r = wv * 8 + d;
                uint4 w0 = *(const uint4*)&wih2_w[r * 512 + ln1 * 4];
                uint4 w1 = *(const uint4*)&wih2_w[r * 512 + ln1 * 4 + 256];
                DOT4(pv[d], w0, hA);
                DOT4(pv[d], w1, hB);
            }
            #pragma unroll
            for (int off = 32; off > 0; off >>= 1) {
                #pragma unroll
                for (int d = 0; d < 8; ++d) pv[d] += __shfl_down(pv[d], off, 64);
            }
            #pragma unroll
            for (int d = 0; d < 8; ++d) pbp[d] = __shfl(pv[d], 0, 64);
        }

        #pragma unroll
        for (int g = 0; g < 4; ++g) pc[g] = pn[g];
    }
}

// ---------------- small matvec ----------------
__global__ __launch_bounds__(256) void linear_vec_kernel(const float* __restrict__ W,
                                                         const float* __restrict__ bias,
                                                         const float* __restrict__ x,
                                                         float* __restrict__ out,
                                                         int N, int K) {
    int wave = threadIdx.x >> 6;
    int lane = threadIdx.x & 63;
    int j = blockIdx.x * 4 + wave;
    if (j >= N) return;
    const float* wr = W + (size_t)j * K;
    float s = 0.0f;
    for (int k = lane; k < K; k += 64) s += wr[k] * x[k];
    #pragma unroll
    for (int off = 32; off > 0; off >>= 1) s += __shfl_down(s, off, 64);
    if (lane == 0) out[j] = s + bias[j];
}

extern "C" void kernel_launch(void* const* d_in, const int* in_sizes, int n_in,
                              void* d_out, int out_size, void* d_ws, size_t ws_size,
                              hipStream_t stream) {
    const float* x_f    = (const float*)d_in[0];
    const float* wih1_f = (const float*)d_in[1];
    const float* whh1_f = (const float*)d_in[2];
    const float* bih1   = (const float*)d_in[3];
    const float* bhh1   = (const float*)d_in[4];
    const float* wih2_f = (const float*)d_in[5];
    const float* whh2_f = (const float*)d_in[6];
    const float* bih2   = (const float*)d_in[7];
    const float* bhh2   = (const float*)d_in[8];
    const float* wl1    = (const float*)d_in[9];
    const float* bl1    = (const float*)d_in[10];
    const float* wl2    = (const float*)d_in[11];
    const float* bl2    = (const float*)d_in[12];

    uint8_t* base = (uint8_t*)d_ws;
    size_t off = 0;
    auto alloc = [&](size_t bytes) { size_t o = off; off = (off + bytes + 255) & ~(size_t)255; return o; };

    size_t pre1_off  = alloc((size_t)T_SEQ * G1 * 2);   // f16 [T,4096]
    size_t comm1_off = alloc((size_t)T_SEQ * H1 * 4);   // f32 [T,1024]
    size_t comm2_off = alloc((size_t)T_SEQ * H2 * 4);   // f32 [T,2048]
    size_t whh1_off  = alloc((size_t)G1 * H1 * 2);
    size_t whh2_off  = alloc((size_t)G2 * H2 * 2);
    size_t wih1_off  = alloc((size_t)G1 * IN_SZ * 2);
    size_t wih2_off  = alloc((size_t)G2 * H1 * 2);
    size_t xb_off    = alloc((size_t)T_SEQ * IN_SZ * 2);
    size_t p1_off    = alloc((size_t)L1OUT * 4);

    f16_t*    pre1  = (f16_t*)(base + pre1_off);
    uint32_t* comm1 = (uint32_t*)(base + comm1_off);
    uint32_t* comm2 = (uint32_t*)(base + comm2_off);
    ushort_t* whh1h = (ushort_t*)(base + whh1_off);
    ushort_t* whh2h = (ushort_t*)(base + whh2_off);
    f16_t*    wih1h = (f16_t*)(base + wih1_off);
    ushort_t* wih2h = (ushort_t*)(base + wih2_off);
    f16_t*    xb    = (f16_t*)(base + xb_off);
    float*    p1    = (float*)(base + p1_off);

    // poison sentinel comm buffers (data-as-signal)
    (void)hipMemsetAsync(comm1, 0xAA, (size_t)T_SEQ * H1 * 4, stream);
    (void)hipMemsetAsync(comm2, 0xAA, (size_t)T_SEQ * H2 * 4, stream);

    // f32 -> f16 conversions
    cvt_f16_kernel<<<2048, 256, 0, stream>>>(x_f,    xb,            T_SEQ * IN_SZ);
    cvt_f16_kernel<<<2048, 256, 0, stream>>>(wih1_f, wih1h,         G1 * IN_SZ);
    cvt_f16_kernel<<<2048, 256, 0, stream>>>(whh1_f, (f16_t*)whh1h, G1 * H1);
    cvt_f16_kernel<<<2048, 256, 0, stream>>>(wih2_f, (f16_t*)wih2h, G2 * H1);
    cvt_f16_kernel<<<4096, 256, 0, stream>>>(whh2_f, (f16_t*)whh2h, G2 * H2);

    // pre1 = x @ wih1^T + (bih1 + bhh1)   [f16 out]
    {
        dim3 grid(G1 / 64, T_SEQ / 64);
        gemm_bt_kernel<<<grid, 256, 0, stream>>>(xb, wih1h, pre1, bih1, bhh1,
                                                 T_SEQ, G1, IN_SZ);
    }

    // fused 2-layer recurrence: 256 blocks, 140KB dynamic LDS
    {
        size_t shmem = (size_t)(16 * 512 + 32 * 512 + 8 * 1024 + 2 * 512 + 2 * 1024) * 4;
        fused_lstm_kernel<<<256, 256, shmem, stream>>>(
            pre1, whh1h, wih2h, whh2h, bih2, bhh2, comm1, comm2, T_SEQ);
    }

    // p1 = wl1 . h2[T-1] + bl1 ; out = wl2 . p1 + bl2
    const float* h2_last = (const float*)(comm2 + (size_t)(T_SEQ - 1) * H2);
    linear_vec_kernel<<<L1OUT / 4, 256, 0, stream>>>(wl1, bl1, h2_last, p1, L1OUT, H2);
    linear_vec_kernel<<<OUT_SZ / 4, 256, 0, stream>>>(wl2, bl2, p1, (float*)d_out, OUT_SZ, L1OUT);

    (void)in_sizes; (void)n_in; (void)out_size; (void)ws_size;
}

// Round 10
// 17552.512 us; speedup vs baseline: 1.6419x; 1.0092x over previous
//
#include <hip/hip_runtime.h>
#include <stdint.h>

typedef unsigned short ushort_t;
typedef _Float16 f16_t;
typedef __attribute__((ext_vector_type(2))) _Float16 half2;
typedef __attribute__((ext_vector_type(8))) _Float16 half8;
typedef __attribute__((ext_vector_type(4))) float f32x4;

#define T_SEQ 4096
#define IN_SZ 512
#define H1 1024
#define H2 2048
#define G1 (4*H1)   // 4096
#define G2 (4*H2)   // 8192
#define OUT_SZ 512
#define L1OUT 1024

// Sentinel 0x7F7F7F7F: as f32 = 3.39e38 (impossible for |h|<=1), as packed f16 both halves
// are NaN (impossible for finite h). Collision-proof, unlike 0xAA patterns.
#define SENT 0x7F7F7F7Fu

__device__ __forceinline__ float f16_val(ushort_t v) {
    union { ushort_t u; _Float16 h; } x; x.u = v; return (float)x.h;
}
__device__ __forceinline__ half2 u2h(uint32_t w) {
    union { uint32_t u; half2 h; } x; x.u = w; return x.h;
}
__device__ __forceinline__ uint32_t pack_f16(float a, float b) {
    auto h = __builtin_amdgcn_cvt_pkrtz(a, b);   // __fp16 ext_vector(2) on gfx950
    union { decltype(h) h; uint32_t u; } x; x.h = h; return x.u;
}
// fast gate math
__device__ __forceinline__ float fsig(float x) {
    return __builtin_amdgcn_rcpf(1.0f + __expf(-x));
}
__device__ __forceinline__ float ftanh(float x) {
    return 1.0f - 2.0f * __builtin_amdgcn_rcpf(__expf(2.0f * x) + 1.0f);
}

// 2 MACs: acc += w·h for one packed f16 pair
__device__ __forceinline__ void dot2(float& acc, uint32_t w, uint32_t h) {
#if defined(__has_builtin) && __has_builtin(__builtin_amdgcn_fdot2)
    acc = __builtin_amdgcn_fdot2(u2h(w), u2h(h), acc, false);
#else
    half2 a = u2h(w), b = u2h(h);
    acc = fmaf((float)a.x, (float)b.x, acc);
    acc = fmaf((float)a.y, (float)b.y, acc);
#endif
}
#define DOT4(ACC, W, Hv) do { dot2(ACC, (W).x, (Hv).x); dot2(ACC, (W).y, (Hv).y); \
                              dot2(ACC, (W).z, (Hv).z); dot2(ACC, (W).w, (Hv).w); } while (0)

// ---------------- f32 -> f16 conversion ----------------
__global__ __launch_bounds__(256) void cvt_f16_kernel(const float* __restrict__ in,
                                                      f16_t* __restrict__ out, int n) {
    int i = blockIdx.x * 256 + threadIdx.x;
    int stride = gridDim.x * 256;
    for (; i < n; i += stride) out[i] = (f16_t)in[i];
}

// ---------------- f16 MFMA GEMM: C[M,N] = A[M,K] * B[N,K]^T + bias_a + bias_b, f16 out ----------
__global__ __launch_bounds__(256) void gemm_bt_kernel(const f16_t* __restrict__ A,
                                                      const f16_t* __restrict__ B,
                                                      f16_t* __restrict__ Cb,
                                                      const float* __restrict__ bias_a,
                                                      const float* __restrict__ bias_b,
                                                      int M, int N, int K) {
    int tid  = threadIdx.x;
    int wave = tid >> 6;
    int lane = tid & 63;
    int l15  = lane & 15;
    int quad = lane >> 4;
    int m0 = blockIdx.y * 64 + wave * 16;
    int n0 = blockIdx.x * 64;

    const f16_t* pa = A + (size_t)(m0 + l15) * K + quad * 8;
    f32x4 acc[4];
    #pragma unroll
    for (int i = 0; i < 4; ++i) acc[i] = (f32x4){0.f, 0.f, 0.f, 0.f};

    for (int kc = 0; kc < K; kc += 32) {
        half8 a = *(const half8*)(pa + kc);
        #pragma unroll
        for (int nf = 0; nf < 4; ++nf) {
            const f16_t* pb = B + (size_t)(n0 + nf * 16 + l15) * K + quad * 8 + kc;
            half8 b = *(const half8*)pb;
            acc[nf] = __builtin_amdgcn_mfma_f32_16x16x32_f16(a, b, acc[nf], 0, 0, 0);
        }
    }

    int rbase = quad * 4;
    #pragma unroll
    for (int nf = 0; nf < 4; ++nf) {
        int n = n0 + nf * 16 + l15;
        float bb = bias_a[n] + bias_b[n];
        #pragma unroll
        for (int r = 0; r < 4; ++r) {
            int m = m0 + rbase + r;
            Cb[(size_t)m * N + n] = (f16_t)(acc[nf][r] + bb);
        }
    }
}

// ---------------- Fused 2-layer LSTM: ONE poll + ONE barrier per iteration ----------------
// 256 blocks x 256 threads (1 block/CU, persistent). Block b owns h1 units [4b,4b+4),
// h2 units [8b,8b+8). Iteration s (s = 0..T+1):
//   poll h1[s-1] (f32) + h2[s-3] (packed f16) -- ONLY the 4 poll loads outstanding, so the
//     poll check's vmcnt drain is clean (R9 entangled wreg/pre1 HBM drain here: ~1us/iter)
//   stage to parity LDS bufs, ONE barrier
//   [issue wreg (whh2 g1..3 from L2) + pre1[s+1] prefetch -- drains under compute shadow]
//   h1[s]   = gates(whh1·h1[s-1] + pre1[s])   -> publish f32      (chain offset ~0.2us)
//   h2[s-2] = gates(whh2·h2[s-3] + pre2[s-2]) -> publish packed f16 via shfl-pair (~0.5us)
//   pre2[s-1] = wih2-slice·h1[s-1]            -> registers for next iteration
__global__ __launch_bounds__(256, 1) void fused_lstm_kernel(
        const f16_t* __restrict__ pre1,       // f16 [T, 4096]
        const ushort_t* __restrict__ whh1h,   // f16 bits [4096, 1024]
        const ushort_t* __restrict__ wih2h,   // f16 bits [8192, 1024]
        const ushort_t* __restrict__ whh2h,   // f16 bits [8192, 2048]
        const float* __restrict__ bih2,
        const float* __restrict__ bhh2,
        uint32_t* __restrict__ comm1,         // f32 bits [T, 1024], pre-poisoned 0x7F
        uint32_t* __restrict__ comm2,         // packed f16 [T, 1024 words], pre-poisoned 0x7F
        int T) {
    extern __shared__ char smem[];
    uint32_t* whh1_w = (uint32_t*)smem;             // [16][512]  f16-pair words (32KB)
    uint32_t* wih2_w = whh1_w + 16 * 512;           // [32][512]  (64KB)
    uint32_t* whh2_w = wih2_w + 32 * 512;           // [8][1024]  gate0 (32KB)
    uint32_t* h1b    = whh2_w + 8 * 1024;           // [2][512]   packed h1 (4KB)
    uint32_t* h2b    = h1b + 2 * 512;               // [2][1024]  packed h2 (8KB)

    int tid = threadIdx.x;
    int blk = blockIdx.x;
    int u1  = tid >> 6;          // h1 unit (0..3), 64 lanes
    int ln1 = tid & 63;
    int u2l = tid >> 5;          // h2 unit (0..7), 32 lanes
    int ln2 = tid & 31;
    int wv  = tid >> 6;          // wave id

    // ---- stage resident weights into LDS ----
    #pragma unroll
    for (int i = 0; i < 8; ++i) {            // whh1: 16 rows x 128 uint4
        int idx = tid + i * 256, r = idx >> 7, ch = idx & 127;
        size_t R = (size_t)(r & 3) * H1 + blk * 4 + (r >> 2);
        *(uint4*)&whh1_w[r * 512 + ch * 4] = *(const uint4*)(whh1h + R * H1 + ch * 8);
    }
    #pragma unroll
    for (int i = 0; i < 16; ++i) {           // wih2: 32 rows x 128 uint4
        int idx = tid + i * 256, r = idx >> 7, ch = idx & 127;
        size_t R = (size_t)(r & 3) * H2 + blk * 8 + (r >> 2);
        *(uint4*)&wih2_w[r * 512 + ch * 4] = *(const uint4*)(wih2h + R * H1 + ch * 8);
    }
    #pragma unroll
    for (int i = 0; i < 8; ++i) {            // whh2 gate0: 8 rows x 256 uint4
        int idx = tid + i * 256, r = idx >> 8, ch = idx & 255;
        size_t R = (size_t)(blk * 8 + r);
        *(uint4*)&whh2_w[r * 1024 + ch * 4] = *(const uint4*)(whh2h + R * H2 + ch * 8);
    }

    float b2g[4];
    {
        int U = blk * 8 + u2l;
        #pragma unroll
        for (int g = 0; g < 4; ++g) b2g[g] = bih2[g * H2 + U] + bhh2[g * H2 + U];
    }

    float pc[4] = {0.f, 0.f, 0.f, 0.f};
    if (ln1 == 0) {
        #pragma unroll
        for (int g = 0; g < 4; ++g)
            pc[g] = f16_val(((const ushort_t*)pre1)[(size_t)0 * G1 + g * H1 + blk * 4 + u1]);
    }

    float c1 = 0.0f;     // ln1==0
    float c2 = 0.0f;     // ln2==0
    float pbp[8];        // pre2[s-2] carried from previous iteration (wave-uniform)
    #pragma unroll
    for (int d = 0; d < 8; ++d) pbp[d] = 0.f;

    for (int s = 0; s <= T + 1; ++s) {
        bool need1 = (s >= 1) & (s <= T);       // h1[s-1] consumer
        bool need2 = (s >= 3) & (s <= T + 1);   // h2[s-3] consumer
        int i1 = need1 ? (s - 1) : 0;
        int i2 = need2 ? (s - 3) : 0;

        // ---- poll FIRST (nothing else outstanding): h1[s-1] f32 + h2[s-3] packed f16 ----
        const uint64_t* s1 = (const uint64_t*)(comm1 + (size_t)i1 * H1);
        const uint64_t* s2 = (const uint64_t*)(comm2 + (size_t)i2 * H2 / 2);
        uint64_t q1[2], q2[2];
        for (;;) {
            q1[0] = __hip_atomic_load(&s1[tid],       __ATOMIC_RELAXED, __HIP_MEMORY_SCOPE_AGENT);
            q1[1] = __hip_atomic_load(&s1[tid + 256], __ATOMIC_RELAXED, __HIP_MEMORY_SCOPE_AGENT);
            q2[0] = __hip_atomic_load(&s2[tid],       __ATOMIC_RELAXED, __HIP_MEMORY_SCOPE_AGENT);
            q2[1] = __hip_atomic_load(&s2[tid + 256], __ATOMIC_RELAXED, __HIP_MEMORY_SCOPE_AGENT);
            bool bad = false;
            if (need1) {
                bad |= ((uint32_t)q1[0] == SENT) | ((uint32_t)(q1[0] >> 32) == SENT)
                     | ((uint32_t)q1[1] == SENT) | ((uint32_t)(q1[1] >> 32) == SENT);
            }
            if (need2) {
                bad |= ((uint32_t)q2[0] == SENT) | ((uint32_t)(q2[0] >> 32) == SENT)
                     | ((uint32_t)q2[1] == SENT) | ((uint32_t)(q2[1] >> 32) == SENT);
            }
            if (!bad) break;
            __builtin_amdgcn_s_sleep(1);
        }

        // ---- stage polled h into parity LDS bufs ----
        if (need1) {
            uint32_t* d = h1b + (s & 1) * 512;
            union { uint64_t q; float f[2]; } x;
            x.q = q1[0]; d[tid]       = pack_f16(x.f[0], x.f[1]);
            x.q = q1[1]; d[tid + 256] = pack_f16(x.f[0], x.f[1]);
        }
        if (need2) {
            uint32_t* d = h2b + (s & 1) * 1024;
            *(uint64_t*)&d[2 * tid]         = q2[0];   // words 2tid, 2tid+1
            *(uint64_t*)&d[2 * (tid + 256)] = q2[1];
        }
        __syncthreads();   // the ONLY barrier per iteration

        // ---- NOW issue prefetches (off the poll path; drain under compute shadow) ----
        uint4 wreg[24];
        if (need2) {
            #pragma unroll
            for (int g = 1; g < 4; ++g) {
                size_t R = (size_t)g * H2 + blk * 8 + u2l;
                #pragma unroll
                for (int j = 0; j < 8; ++j)
                    wreg[(g - 1) * 8 + j] =
                        *(const uint4*)(whh2h + R * H2 + ln2 * 8 + j * 256);
            }
        }
        float pn[4] = {0.f, 0.f, 0.f, 0.f};
        if (ln1 == 0) {
            int row = (s + 1 < T) ? s + 1 : T - 1;
            #pragma unroll
            for (int g = 0; g < 4; ++g)
                pn[g] = f16_val(((const ushort_t*)pre1)[(size_t)row * G1 + g * H1 + blk * 4 + u1]);
        }

        const uint32_t* h1p = h1b + (s & 1) * 512;
        uint4 hA, hB;
        if (need1) {
            hA = *(const uint4*)&h1p[ln1 * 4];
            hB = *(const uint4*)&h1p[ln1 * 4 + 256];
        }

        // ---- h1[s]: dot + gates + immediate publish ----
        if (s < T) {
            float a0 = 0.f, a1 = 0.f, a2 = 0.f, a3 = 0.f;
            if (s >= 1) {
                uint4 w;
                w = *(const uint4*)&whh1_w[(u1 * 4 + 0) * 512 + ln1 * 4];       DOT4(a0, w, hA);
                w = *(const uint4*)&whh1_w[(u1 * 4 + 0) * 512 + ln1 * 4 + 256]; DOT4(a0, w, hB);
                w = *(const uint4*)&whh1_w[(u1 * 4 + 1) * 512 + ln1 * 4];       DOT4(a1, w, hA);
                w = *(const uint4*)&whh1_w[(u1 * 4 + 1) * 512 + ln1 * 4 + 256]; DOT4(a1, w, hB);
                w = *(const uint4*)&whh1_w[(u1 * 4 + 2) * 512 + ln1 * 4];       DOT4(a2, w, hA);
                w = *(const uint4*)&whh1_w[(u1 * 4 + 2) * 512 + ln1 * 4 + 256]; DOT4(a2, w, hB);
                w = *(const uint4*)&whh1_w[(u1 * 4 + 3) * 512 + ln1 * 4];       DOT4(a3, w, hA);
                w = *(const uint4*)&whh1_w[(u1 * 4 + 3) * 512 + ln1 * 4 + 256]; DOT4(a3, w, hB);
            }
            #pragma unroll
            for (int off = 32; off > 0; off >>= 1) {
                a0 += __shfl_down(a0, off, 64); a1 += __shfl_down(a1, off, 64);
                a2 += __shfl_down(a2, off, 64); a3 += __shfl_down(a3, off, 64);
            }
            if (ln1 == 0) {
                float iv = fsig(pc[0] + a0);
                float fv = fsig(pc[1] + a1);
                float gv = ftanh(pc[2] + a2);
                float ov = fsig(pc[3] + a3);
                c1 = fv * c1 + iv * gv;
                float h = ov * ftanh(c1);
                union { float f; uint32_t u; } x; x.f = h;
                __hip_atomic_store(&comm1[(size_t)s * H1 + blk * 4 + u1], x.u,
                                   __ATOMIC_RELAXED, __HIP_MEMORY_SCOPE_AGENT);
            }
        }

        // ---- h2[s-2] = gates(whh2·h2[s-3] + pre2[s-2]); publish packed f16 via shfl pair ----
        if (s >= 2) {
            float b0 = 0.f, b1 = 0.f, b2 = 0.f, b3 = 0.f;
            if (need2) {
                const uint32_t* h2p = h2b + (s & 1) * 1024;
                #pragma unroll
                for (int j = 0; j < 8; ++j) {
                    uint4 hx = *(const uint4*)&h2p[ln2 * 4 + j * 128];
                    uint4 w0 = *(const uint4*)&whh2_w[u2l * 1024 + ln2 * 4 + j * 128];
                    DOT4(b0, w0, hx);
                    DOT4(b1, wreg[j], hx);
                    DOT4(b2, wreg[8 + j], hx);
                    DOT4(b3, wreg[16 + j], hx);
                }
            }
            #pragma unroll
            for (int off = 16; off > 0; off >>= 1) {
                b0 += __shfl_down(b0, off, 32); b1 += __shfl_down(b1, off, 32);
                b2 += __shfl_down(b2, off, 32); b3 += __shfl_down(b3, off, 32);
            }
            float h = 0.0f;
            if (ln2 == 0) {
                int half = u2l & 1;
                float iv = fsig(pbp[half * 4 + 0] + b2g[0] + b0);
                float fv = fsig(pbp[half * 4 + 1] + b2g[1] + b1);
                float gv = ftanh(pbp[half * 4 + 2] + b2g[2] + b2);
                float ov = fsig(pbp[half * 4 + 3] + b2g[3] + b3);
                c2 = fv * c2 + iv * gv;
                h = ov * ftanh(c2);
            }
            // partner unit (u2l odd) sits 32 lanes up in the same wave
            float hpart = __shfl_down(h, 32, 64);
            if ((tid & 63) == 0) {
                uint32_t word = pack_f16(h, hpart);
                __hip_atomic_store(&comm2[(size_t)(s - 2) * 1024 + blk * 4 + wv], word,
                                   __ATOMIC_RELAXED, __HIP_MEMORY_SCOPE_AGENT);
            }
        }

        // ---- pre2[s-1] = wih2-slice · h1[s-1] (for NEXT iteration; off the publish path) ----
        if (need1) {
            float pv[8];
            #pragma unroll
            for (int d = 0; d < 8; ++d) pv[d] = 0.f;
            #pragma unroll
            for (int d = 0; d < 8; ++d) {
                int r = wv * 8 + d;
                uint4 w0 = *(const uint4*)&wih2_w[r * 512 + ln1 * 4];
                uint4 w1 = *(const uint4*)&wih2_w[r * 512 + ln1 * 4 + 256];
                DOT4(pv[d], w0, hA);
                DOT4(pv[d], w1, hB);
            }
            #pragma unroll
            for (int off = 32; off > 0; off >>= 1) {
                #pragma unroll
                for (int d = 0; d < 8; ++d) pv[d] += __shfl_down(pv[d], off, 64);
            }
            #pragma unroll
            for (int d = 0; d < 8; ++d) pbp[d] = __shfl(pv[d], 0, 64);
        }

        #pragma unroll
        for (int g = 0; g < 4; ++g) pc[g] = pn[g];
    }
}

// ---------------- p1[j] = wl1[j,:] · unpack_f16(x_words) + bias[j] ----------------
__global__ __launch_bounds__(256) void linear_vec_f16x_kernel(const float* __restrict__ W,
                                                              const float* __restrict__ bias,
                                                              const uint32_t* __restrict__ xw,
                                                              float* __restrict__ out,
                                                              int N, int Kw) {  // Kw = K/2 words
    int wave = threadIdx.x >> 6;
    int lane = threadIdx.x & 63;
    int j = blockIdx.x * 4 + wave;
    if (j >= N) return;
    const float* wr = W + (size_t)j * (Kw * 2);
    float s = 0.0f;
    for (int w = lane; w < Kw; w += 64) {
        half2 h = u2h(xw[w]);
        s = fmaf((float)h.x, wr[2 * w],     s);
        s = fmaf((float)h.y, wr[2 * w + 1], s);
    }
    #pragma unroll
    for (int off = 32; off > 0; off >>= 1) s += __shfl_down(s, off, 64);
    if (lane == 0) out[j] = s + bias[j];
}

// ---------------- small matvec (f32 x) ----------------
__global__ __launch_bounds__(256) void linear_vec_kernel(const float* __restrict__ W,
                                                         const float* __restrict__ bias,
                                                         const float* __restrict__ x,
                                                         float* __restrict__ out,
                                                         int N, int K) {
    int wave = threadIdx.x >> 6;
    int lane = threadIdx.x & 63;
    int j = blockIdx.x * 4 + wave;
    if (j >= N) return;
    const float* wr = W + (size_t)j * K;
    float s = 0.0f;
    for (int k = lane; k < K; k += 64) s += wr[k] * x[k];
    #pragma unroll
    for (int off = 32; off > 0; off >>= 1) s += __shfl_down(s, off, 64);
    if (lane == 0) out[j] = s + bias[j];
}

extern "C" void kernel_launch(void* const* d_in, const int* in_sizes, int n_in,
                              void* d_out, int out_size, void* d_ws, size_t ws_size,
                              hipStream_t stream) {
    const float* x_f    = (const float*)d_in[0];
    const float* wih1_f = (const float*)d_in[1];
    const float* whh1_f = (const float*)d_in[2];
    const float* bih1   = (const float*)d_in[3];
    const float* bhh1   = (const float*)d_in[4];
    const float* wih2_f = (const float*)d_in[5];
    const float* whh2_f = (const float*)d_in[6];
    const float* bih2   = (const float*)d_in[7];
    const float* bhh2   = (const float*)d_in[8];
    const float* wl1    = (const float*)d_in[9];
    const float* bl1    = (const float*)d_in[10];
    const float* wl2    = (const float*)d_in[11];
    const float* bl2    = (const float*)d_in[12];

    uint8_t* base = (uint8_t*)d_ws;
    size_t off = 0;
    auto alloc = [&](size_t bytes) { size_t o = off; off = (off + bytes + 255) & ~(size_t)255; return o; };

    size_t pre1_off  = alloc((size_t)T_SEQ * G1 * 2);   // f16 [T,4096]
    size_t comm1_off = alloc((size_t)T_SEQ * H1 * 4);   // f32 [T,1024]
    size_t comm2_off = alloc((size_t)T_SEQ * H2 * 2);   // packed f16 [T,1024 words]
    size_t whh1_off  = alloc((size_t)G1 * H1 * 2);
    size_t whh2_off  = alloc((size_t)G2 * H2 * 2);
    size_t wih1_off  = alloc((size_t)G1 * IN_SZ * 2);
    size_t wih2_off  = alloc((size_t)G2 * H1 * 2);
    size_t xb_off    = alloc((size_t)T_SEQ * IN_SZ * 2);
    size_t p1_off    = alloc((size_t)L1OUT * 4);

    f16_t*    pre1  = (f16_t*)(base + pre1_off);
    uint32_t* comm1 = (uint32_t*)(base + comm1_off);
    uint32_t* comm2 = (uint32_t*)(base + comm2_off);
    ushort_t* whh1h = (ushort_t*)(base + whh1_off);
    ushort_t* whh2h = (ushort_t*)(base + whh2_off);
    f16_t*    wih1h = (f16_t*)(base + wih1_off);
    ushort_t* wih2h = (ushort_t*)(base + wih2_off);
    f16_t*    xb    = (f16_t*)(base + xb_off);
    float*    p1    = (float*)(base + p1_off);

    // poison sentinel comm buffers with 0x7F bytes (data-as-signal; see SENT comment)
    (void)hipMemsetAsync(comm1, 0x7F, (size_t)T_SEQ * H1 * 4, stream);
    (void)hipMemsetAsync(comm2, 0x7F, (size_t)T_SEQ * H2 * 2, stream);

    // f32 -> f16 conversions
    cvt_f16_kernel<<<2048, 256, 0, stream>>>(x_f,    xb,            T_SEQ * IN_SZ);
    cvt_f16_kernel<<<2048, 256, 0, stream>>>(wih1_f, wih1h,         G1 * IN_SZ);
    cvt_f16_kernel<<<2048, 256, 0, stream>>>(whh1_f, (f16_t*)whh1h, G1 * H1);
    cvt_f16_kernel<<<2048, 256, 0, stream>>>(wih2_f, (f16_t*)wih2h, G2 * H1);
    cvt_f16_kernel<<<4096, 256, 0, stream>>>(whh2_f, (f16_t*)whh2h, G2 * H2);

    // pre1 = x @ wih1^T + (bih1 + bhh1)   [f16 out]
    {
        dim3 grid(G1 / 64, T_SEQ / 64);
        gemm_bt_kernel<<<grid, 256, 0, stream>>>(xb, wih1h, pre1, bih1, bhh1,
                                                 T_SEQ, G1, IN_SZ);
    }

    // fused 2-layer recurrence: 256 blocks, 140KB dynamic LDS
    {
        size_t shmem = (size_t)(16 * 512 + 32 * 512 + 8 * 1024 + 2 * 512 + 2 * 1024) * 4;
        fused_lstm_kernel<<<256, 256, shmem, stream>>>(
            pre1, whh1h, wih2h, whh2h, bih2, bhh2, comm1, comm2, T_SEQ);
    }

    // p1 = wl1 . h2[T-1] + bl1 ; out = wl2 . p1 + bl2
    const uint32_t* h2_last = comm2 + (size_t)(T_SEQ - 1) * (H2 / 2);
    linear_vec_f16x_kernel<<<L1OUT / 4, 256, 0, stream>>>(wl1, bl1, h2_last, p1, L1OUT, H2 / 2);
    linear_vec_kernel<<<OUT_SZ / 4, 256, 0, stream>>>(wl2, bl2, p1, (float*)d_out, OUT_SZ, L1OUT);

    (void)in_sizes; (void)n_in; (void)out_size; (void)ws_size;
}